// Round 24
// baseline (308.237 us; speedup 1.0000x reference)
//
#include <hip/hip_runtime.h>

#define N_AUTHORS 50000
#define N_PAPERS  100000
#define N_NODES   150000
#define N_EDGES   1200000
#define EMB       64
#define COL_SPLIT 75000u

#define BSHIFT 10
#define K_B    ((N_NODES + 1023) >> 10)           // 147 row-buckets (1024 rows each)
#define CHUNK  4096                               // edges per A-block
#define NBLK_A ((N_EDGES + CHUNK - 1) / CHUNK)    // 293
#define NSC    (K_B * NBLK_A)                     // 43071 (bucket-major counts)
#define NBS1   ((NSC + 1023) / 1024)              // 43 L1-scan blocks

typedef float v2f __attribute__((ext_vector_type(2)));

// bf16 helpers (plain ushort storage)
__device__ __forceinline__ ushort f2bf(float f) {   // round-to-nearest-even
    unsigned u = __float_as_uint(f);
    return (ushort)((u + 0x7fffu + ((u >> 16) & 1u)) >> 16);
}
#define bfLO(u) __uint_as_float((u) << 16)
#define bfHI(u) __uint_as_float((u) & 0xffff0000u)

__device__ __forceinline__ v2f mkv2(float a, float b) { v2f r; r.x = a; r.y = b; return r; }
__device__ __forceinline__ v2f bfv2(unsigned u) { return mkv2(bfLO(u), bfHI(u)); }

// v2f butterfly reduce across edge-slot groups (xor 8/16/32)
__device__ __forceinline__ v2f red_v2(v2f v) {
#pragma unroll
    for (int s = 8; s <= 32; s <<= 1) {
        v2f o;
        o.x = __shfl_xor(v.x, s, 64);
        o.y = __shfl_xor(v.y, s, 64);
        v += o;
    }
    return v;
}

// ---------------- fused: bucket-major histogram (blocks 0..NBLK_A-1)
//                  + init ego f32/bf16 (blocks NBLK_A..) ---------------------
__global__ void lgcn_hist_init(const int* __restrict__ rows,
                               unsigned* __restrict__ counts,
                               const float* __restrict__ a,
                               const float* __restrict__ p,
                               float* __restrict__ ego_out,
                               ushort* __restrict__ x0) {
    __shared__ unsigned h[K_B];
    int t = threadIdx.x;
    if (blockIdx.x < NBLK_A) {
        for (int i = t; i < K_B; i += blockDim.x) h[i] = 0;
        __syncthreads();
        int base = blockIdx.x * CHUNK;
        int end  = base + CHUNK; if (end > N_EDGES) end = N_EDGES;
        for (int e = base + t; e < end; e += blockDim.x)
            atomicAdd(&h[rows[e] >> BSHIFT], 1u);
        __syncthreads();
        for (int i = t; i < K_B; i += blockDim.x)
            counts[(size_t)i * NBLK_A + blockIdx.x] = h[i];
    } else {
        size_t i = (size_t)(blockIdx.x - NBLK_A) * blockDim.x + t;  // float4 idx
        const size_t n4  = (size_t)N_NODES  * EMB / 4;
        const size_t au4 = (size_t)N_AUTHORS * EMB / 4;
        if (i >= n4) return;
        float4 v = (i < au4) ? ((const float4*)a)[i] : ((const float4*)p)[i - au4];
        ((float4*)ego_out)[i] = v;
        ushort4 b;
        b.x = f2bf(v.x); b.y = f2bf(v.y); b.z = f2bf(v.z); b.w = f2bf(v.w);
        ((ushort4*)x0)[i] = b;
    }
}

// ---------------- L1 scan over NSC entries (block totals -> btot) -----------
__global__ void lgcn_scan_l1(const unsigned* __restrict__ counts,
                             unsigned* __restrict__ scanned,
                             unsigned* __restrict__ btot) {
    __shared__ unsigned s[1024];
    int t = threadIdx.x;
    int i = blockIdx.x * 1024 + t;
    unsigned v = (i < NSC) ? counts[i] : 0u;
    s[t] = v;
    __syncthreads();
    for (int d = 1; d < 1024; d <<= 1) {
        unsigned u = (t >= d) ? s[t - d] : 0u;
        __syncthreads();
        s[t] += u;
        __syncthreads();
    }
    if (i < NSC) scanned[i] = s[t] - v;     // exclusive within block
    if (t == 1023) btot[blockIdx.x] = s[1023];
}

// in-block top-level prefix of btot (43 entries) -> LDS
__device__ __forceinline__ void btot_prefix(const unsigned* __restrict__ btot,
                                            unsigned* __restrict__ btex) {
    if (threadIdx.x == 0) {
        unsigned run = 0;
        for (int i = 0; i < NBS1; ++i) { btex[i] = run; run += btot[i]; }
    }
    __syncthreads();
}

// ---------------- A1: bin edges into EXCLUSIVE per-(block,bucket) runs ------
__global__ void lgcn_a1_bin(const int* __restrict__ rows,
                            const int* __restrict__ cols,
                            const float* __restrict__ vals,
                            const unsigned* __restrict__ scanned,
                            const unsigned* __restrict__ btot,
                            float2* __restrict__ stage) {
    __shared__ unsigned cur[K_B];
    __shared__ unsigned btex[NBS1];
    btot_prefix(btot, btex);
    int t = threadIdx.x;
    for (int i = t; i < K_B; i += blockDim.x) {
        unsigned idx = (unsigned)i * NBLK_A + blockIdx.x;
        cur[i] = scanned[idx] + btex[idx >> 10];
    }
    __syncthreads();
    int base = blockIdx.x * CHUNK;
    int end  = base + CHUNK; if (end > N_EDGES) end = N_EDGES;
    for (int e = base + t; e < end; e += blockDim.x) {
        int r = rows[e];
        unsigned pos = atomicAdd(&cur[r >> BSHIFT], 1u);
        unsigned packed = ((unsigned)(r & 1023) << 18) | (unsigned)cols[e];
        stage[pos] = make_float2(__uint_as_float(packed), vals[e]);
    }
}

// ---------------- B: per-bucket place; sorts (row, col-panel); emits
//                  row_start + row_mid --------------------------------------
__global__ void lgcn_place(const unsigned* __restrict__ scanned,
                           const unsigned* __restrict__ btot,
                           const float2* __restrict__ stage,
                           float2* __restrict__ se,
                           unsigned* __restrict__ row_start,
                           unsigned* __restrict__ row_mid) {
    __shared__ unsigned cur[2048];          // bins: rowlo*2 + panel
    __shared__ unsigned tsum[256];
    __shared__ unsigned btex[NBS1];
    btot_prefix(btot, btex);
    int b  = blockIdx.x;
    int rb = b << BSHIFT;
    int nrows = N_NODES - rb; if (nrows > (1 << BSHIFT)) nrows = 1 << BSHIFT;
    int t = threadIdx.x;

    unsigned i0 = (unsigned)b * NBLK_A;
    unsigned base = scanned[i0] + btex[i0 >> 10];
    unsigned span1;
    if (b + 1 < K_B) {
        unsigned i1 = (unsigned)(b + 1) * NBLK_A;
        span1 = scanned[i1] + btex[i1 >> 10];
    } else span1 = N_EDGES;

    // pass 1: count (rowlo, panel) bins from staged records (L2-hot span)
    for (int i = t; i < 2048; i += 256) cur[i] = 0;
    __syncthreads();
    for (unsigned p = base + t; p < span1; p += 256) {
        unsigned u = __float_as_uint(stage[p].x);
        unsigned bin = ((u >> 18) << 1) | ((u & 0x3FFFFu) >= COL_SPLIT ? 1u : 0u);
        atomicAdd(&cur[bin], 1u);
    }
    __syncthreads();

    // block scan of the 2048 bin counts (8 per thread) -> cursors + spans
    unsigned c[8], s = 0;
#pragma unroll
    for (int k = 0; k < 8; ++k) { c[k] = cur[t * 8 + k]; s += c[k]; }
    tsum[t] = s;
    __syncthreads();
    for (int d = 1; d < 256; d <<= 1) {
        unsigned u = (t >= d) ? tsum[t - d] : 0u;
        __syncthreads();
        tsum[t] += u;
        __syncthreads();
    }
    unsigned run = base + (tsum[t] - s);
    __syncthreads();            // everyone done reading cur before overwrite
#pragma unroll
    for (int k = 0; k < 8; ++k) {
        int bin = t * 8 + k;
        cur[bin] = run;
        int row = bin >> 1;
        if (row < nrows) {
            if ((bin & 1) == 0) row_start[rb + row] = run;
            else                row_mid[rb + row]   = run;
        }
        run += c[k];
    }
    if (b == K_B - 1 && t == 0) row_start[N_NODES] = N_EDGES;
    __syncthreads();

    // pass 2: place into (row, panel)-sorted se
    for (unsigned p = base + t; p < span1; p += 256) {
        float2 v = stage[p];
        unsigned u = __float_as_uint(v.x);
        unsigned col = u & 0x3FFFFu;
        unsigned bin = ((u >> 18) << 1) | (col >= COL_SPLIT ? 1u : 0u);
        unsigned pos = atomicAdd(&cur[bin], 1u);
        se[pos] = make_float2(__int_as_float((int)col), v.y);
    }
}

// ---------------- SpMM: col-panel passes, one wave per 2 rows ---------------
// PASS 0: gather panel-A cols only, write bf16 partial yp.
// PASS 1: gather panel-B cols, add yp, emit per MODE.
// MODE 0: gather bf16 (xb). MODE 1/2: gather fp8 (x8). MODE 2 fuses merge.
template <int MODE, int PASS>
__global__ void lgcn_spmm(const unsigned* __restrict__ rs,
                          const unsigned* __restrict__ rmid,
                          const float2* __restrict__ se,
                          const ushort* __restrict__ xb,
                          const unsigned char* __restrict__ x8,
                          ushort* __restrict__ yp,
                          unsigned char* __restrict__ y8,
                          const ushort* __restrict__ egob,
                          const unsigned char* __restrict__ y18,
                          float* __restrict__ out) {
    int w    = blockIdx.x * (blockDim.x >> 6) + (threadIdx.x >> 6);
    int lane = threadIdx.x & 63;
    int r0   = w << 1;
    if (r0 >= N_NODES) return;
    unsigned jA, endA, jB, endB;
    if constexpr (PASS == 0) {
        jA = rs[r0];       endA = rmid[r0];
        jB = rs[r0 + 1];   endB = rmid[r0 + 1];
    } else {
        jA = rmid[r0];     endA = rs[r0 + 1];
        jB = rmid[r0 + 1]; endB = rs[r0 + 2];
    }
    const int g  = lane >> 3;
    const int d8 = (lane & 7) << 3;    // 8 bf16 elements or 8 fp8 bytes
    v2f A0 = {0.f, 0.f}, A1 = A0, A2 = A0, A3 = A0;
    v2f B0 = A0, B1 = A0, B2 = A0, B3 = A0;

#define BATCH8(JB, END, P0, P1, P2, P3)                                       \
    {                                                                         \
        unsigned idx = (JB) + g;                                              \
        float2 e;                                                             \
        if (idx < (END)) e = se[idx];                                         \
        else { e.x = __int_as_float(0); e.y = 0.f; }                          \
        v2f ey = mkv2(e.y, e.y);                                              \
        if constexpr (MODE == 0) {                                            \
            const uint4 xv = *(const uint4*)(xb + ((size_t)__float_as_int(e.x) << 6) + d8); \
            P0 += ey * bfv2(xv.x);                                            \
            P1 += ey * bfv2(xv.y);                                            \
            P2 += ey * bfv2(xv.z);                                            \
            P3 += ey * bfv2(xv.w);                                            \
        } else {                                                              \
            const uint2 xv = *(const uint2*)(x8 + ((size_t)__float_as_int(e.x) << 6) + d8); \
            P0 += ey * __builtin_amdgcn_cvt_pk_f32_fp8((int)xv.x, false);     \
            P1 += ey * __builtin_amdgcn_cvt_pk_f32_fp8((int)xv.x, true);      \
            P2 += ey * __builtin_amdgcn_cvt_pk_f32_fp8((int)xv.y, false);     \
            P3 += ey * __builtin_amdgcn_cvt_pk_f32_fp8((int)xv.y, true);      \
        }                                                                     \
    }

    // both rows' first batches issued back-to-back
    BATCH8(jA, endA, A0, A1, A2, A3)
    BATCH8(jB, endB, B0, B1, B2, B3)
    jA += 8; jB += 8;
    while (jA < endA) { BATCH8(jA, endA, A0, A1, A2, A3) jA += 8; }
    while (jB < endB) { BATCH8(jB, endB, B0, B1, B2, B3) jB += 8; }
#undef BATCH8

    A0 = red_v2(A0); A1 = red_v2(A1); A2 = red_v2(A2); A3 = red_v2(A3);
    B0 = red_v2(B0); B1 = red_v2(B1); B2 = red_v2(B2); B3 = red_v2(B3);

    if (g == 0) {
#define EMIT(ROW, P0, P1, P2, P3)                                             \
    {                                                                         \
        size_t o = ((size_t)(ROW) << 6) + d8;                                 \
        if constexpr (PASS == 0) {                                            \
            uint4 ov;                                                         \
            ov.x = (unsigned)f2bf(P0.x) | ((unsigned)f2bf(P0.y) << 16);       \
            ov.y = (unsigned)f2bf(P1.x) | ((unsigned)f2bf(P1.y) << 16);       \
            ov.z = (unsigned)f2bf(P2.x) | ((unsigned)f2bf(P2.y) << 16);       \
            ov.w = (unsigned)f2bf(P3.x) | ((unsigned)f2bf(P3.y) << 16);       \
            *(uint4*)(yp + o) = ov;                                           \
        } else {                                                              \
            uint4 pv = *(const uint4*)(yp + o);                               \
            P0 += bfv2(pv.x); P1 += bfv2(pv.y);                               \
            P2 += bfv2(pv.z); P3 += bfv2(pv.w);                               \
            if constexpr (MODE == 2) {                                        \
                uint4 ue = *(const uint4*)(egob + o);                         \
                uint2 u1 = *(const uint2*)(y18 + o);                          \
                uint2 u2 = *(const uint2*)(x8 + o);                           \
                v2f q = mkv2(0.25f, 0.25f);                                   \
                v2f r0v = (bfv2(ue.x) + __builtin_amdgcn_cvt_pk_f32_fp8((int)u1.x, false) \
                          + __builtin_amdgcn_cvt_pk_f32_fp8((int)u2.x, false) + P0) * q; \
                v2f r1v = (bfv2(ue.y) + __builtin_amdgcn_cvt_pk_f32_fp8((int)u1.x, true)  \
                          + __builtin_amdgcn_cvt_pk_f32_fp8((int)u2.x, true) + P1) * q; \
                v2f r2v = (bfv2(ue.z) + __builtin_amdgcn_cvt_pk_f32_fp8((int)u1.y, false) \
                          + __builtin_amdgcn_cvt_pk_f32_fp8((int)u2.y, false) + P2) * q; \
                v2f r3v = (bfv2(ue.w) + __builtin_amdgcn_cvt_pk_f32_fp8((int)u1.y, true)  \
                          + __builtin_amdgcn_cvt_pk_f32_fp8((int)u2.y, true) + P3) * q; \
                float4 lo, hi;                                                \
                lo.x = r0v.x; lo.y = r0v.y; lo.z = r1v.x; lo.w = r1v.y;       \
                hi.x = r2v.x; hi.y = r2v.y; hi.z = r3v.x; hi.w = r3v.y;       \
                *(float4*)(out + o)     = lo;                                 \
                *(float4*)(out + o + 4) = hi;                                 \
            } else {                                                          \
                int w0 = __builtin_amdgcn_cvt_pk_fp8_f32(P0.x, P0.y, 0, false); \
                w0     = __builtin_amdgcn_cvt_pk_fp8_f32(P1.x, P1.y, w0, true); \
                int w1 = __builtin_amdgcn_cvt_pk_fp8_f32(P2.x, P2.y, 0, false); \
                w1     = __builtin_amdgcn_cvt_pk_fp8_f32(P3.x, P3.y, w1, true); \
                uint2 ov8; ov8.x = (unsigned)w0; ov8.y = (unsigned)w1;        \
                *(uint2*)(y8 + o) = ov8;                                      \
            }                                                                 \
        }                                                                     \
    }
        EMIT(r0, A0, A1, A2, A3)
        EMIT(r0 + 1, B0, B1, B2, B3)
#undef EMIT
    }
}

extern "C" void kernel_launch(void* const* d_in, const int* in_sizes, int n_in,
                              void* d_out, int out_size, void* d_ws, size_t ws_size,
                              hipStream_t stream) {
    const float* author = (const float*)d_in[0];
    const float* paper  = (const float*)d_in[1];
    const int*   rows   = (const int*)d_in[2];
    const int*   cols   = (const int*)d_in[3];
    const float* vals   = (const float*)d_in[4];

    float* ego_out = (float*)d_out;                           // 150000*64 f32
    float* acc     = (float*)d_out + (size_t)N_NODES * EMB;   // author||paper f32

    // workspace layout (~70 MB)
    char* w = (char*)d_ws;
    float2*   se        = (float2*)w;   w += (size_t)N_EDGES * sizeof(float2);       // 9.6 MB
    float2*   stage     = (float2*)w;   w += (size_t)N_EDGES * sizeof(float2);       // 9.6 MB (dead after place -> y1_8)
    ushort*   xbE       = (ushort*)w;   w += (size_t)N_NODES * EMB * sizeof(ushort); // 19.2 MB (bf16 ego)
    ushort*   yp        = (ushort*)w;   w += (size_t)N_NODES * EMB * sizeof(ushort); // 19.2 MB (bf16 partial)
    unsigned char* y2_8 = (unsigned char*)w; w += (size_t)N_NODES * EMB;             // 9.6 MB (fp8 y2)
    unsigned* row_start = (unsigned*)w; w += (size_t)(N_NODES + 1) * 4;              // 0.6 MB
    unsigned* row_mid   = (unsigned*)w; w += (size_t)N_NODES * 4;                    // 0.6 MB
    unsigned* bcounts   = (unsigned*)w; w += (size_t)NSC * 4;                        // 172 KB
    unsigned* bscanned  = (unsigned*)w; w += (size_t)NSC * 4;                        // 172 KB
    unsigned* btot      = (unsigned*)w; w += 64 * 4;
    unsigned char* y1_8 = (unsigned char*)stage;   // alias: stage dead after place

    const int BLK = 256;
    const int g_vec  = (int)(((size_t)N_NODES * EMB / 4 + BLK - 1) / BLK);
    const int g_spmm = ((N_NODES / 2) + 3) / 4;       // 2 rows/wave, 4 waves/block

    // fused: bucket histogram + ego init
    lgcn_hist_init<<<NBLK_A + g_vec, BLK, 0, stream>>>(rows, bcounts,
                                                       author, paper, ego_out, xbE);

    // L1 scan (top-level prefix folded into consumers)
    lgcn_scan_l1<<<NBS1, 1024, 0, stream>>>(bcounts, bscanned, btot);

    // bin into exclusive staging runs, then place (row,panel sort + spans)
    lgcn_a1_bin<<<NBLK_A, BLK, 0, stream>>>(rows, cols, vals, bscanned, btot, stage);
    lgcn_place<<<K_B, BLK, 0, stream>>>(bscanned, btot, stage, se, row_start, row_mid);

    // L1: gather bf16 ego -> y1 fp8 (2 col-panel passes)
    lgcn_spmm<0, 0><<<g_spmm, BLK, 0, stream>>>(row_start, row_mid, se, xbE, nullptr,
                                                yp, nullptr, nullptr, nullptr, nullptr);
    lgcn_spmm<0, 1><<<g_spmm, BLK, 0, stream>>>(row_start, row_mid, se, xbE, nullptr,
                                                yp, y1_8, nullptr, nullptr, nullptr);
    // L2: gather fp8 y1 -> y2 fp8
    lgcn_spmm<1, 0><<<g_spmm, BLK, 0, stream>>>(row_start, row_mid, se, nullptr, y1_8,
                                                yp, nullptr, nullptr, nullptr, nullptr);
    lgcn_spmm<1, 1><<<g_spmm, BLK, 0, stream>>>(row_start, row_mid, se, nullptr, y1_8,
                                                yp, y2_8, nullptr, nullptr, nullptr);
    // L3: gather fp8 y2, fused merge -> out
    lgcn_spmm<2, 0><<<g_spmm, BLK, 0, stream>>>(row_start, row_mid, se, nullptr, y2_8,
                                                yp, nullptr, nullptr, nullptr, nullptr);
    lgcn_spmm<2, 1><<<g_spmm, BLK, 0, stream>>>(row_start, row_mid, se, nullptr, y2_8,
                                                yp, nullptr, xbE, y1_8, acc);
}

// Round 25
// 191.834 us; speedup vs baseline: 1.6068x; 1.6068x over previous
//
#include <hip/hip_runtime.h>

#define N_AUTHORS 50000
#define N_PAPERS  100000
#define N_NODES   150000
#define N_EDGES   1200000
#define EMB       64

#define BSHIFT 10
#define K_B    ((N_NODES + 1023) >> 10)           // 147 row-buckets (1024 rows each)
#define CHUNK  4096                               // edges per A-block
#define NBLK_A ((N_EDGES + CHUNK - 1) / CHUNK)    // 293
#define NSC    (K_B * NBLK_A)                     // 43071 (bucket-major counts)
#define NBS1   ((NSC + 1023) / 1024)              // 43 L1-scan blocks

typedef float v2f __attribute__((ext_vector_type(2)));

// bf16 helpers (plain ushort storage)
__device__ __forceinline__ ushort f2bf(float f) {   // round-to-nearest-even
    unsigned u = __float_as_uint(f);
    return (ushort)((u + 0x7fffu + ((u >> 16) & 1u)) >> 16);
}
#define bfLO(u) __uint_as_float((u) << 16)
#define bfHI(u) __uint_as_float((u) & 0xffff0000u)

__device__ __forceinline__ v2f mkv2(float a, float b) { v2f r; r.x = a; r.y = b; return r; }
__device__ __forceinline__ v2f bfv2(unsigned u) { return mkv2(bfLO(u), bfHI(u)); }

// v2f butterfly reduce across edge-slot groups (xor 8/16/32)
__device__ __forceinline__ v2f red_v2(v2f v) {
#pragma unroll
    for (int s = 8; s <= 32; s <<= 1) {
        v2f o;
        o.x = __shfl_xor(v.x, s, 64);
        o.y = __shfl_xor(v.y, s, 64);
        v += o;
    }
    return v;
}

// ---------------- fused: bucket-major histogram (blocks 0..NBLK_A-1)
//                  + init ego f32/bf16 (blocks NBLK_A..) ---------------------
__global__ void lgcn_hist_init(const int* __restrict__ rows,
                               unsigned* __restrict__ counts,
                               const float* __restrict__ a,
                               const float* __restrict__ p,
                               float* __restrict__ ego_out,
                               ushort* __restrict__ x0) {
    __shared__ unsigned h[K_B];
    int t = threadIdx.x;
    if (blockIdx.x < NBLK_A) {
        for (int i = t; i < K_B; i += blockDim.x) h[i] = 0;
        __syncthreads();
        int base = blockIdx.x * CHUNK;
        int end  = base + CHUNK; if (end > N_EDGES) end = N_EDGES;
        for (int e = base + t; e < end; e += blockDim.x)
            atomicAdd(&h[rows[e] >> BSHIFT], 1u);
        __syncthreads();
        for (int i = t; i < K_B; i += blockDim.x)
            counts[(size_t)i * NBLK_A + blockIdx.x] = h[i];
    } else {
        size_t i = (size_t)(blockIdx.x - NBLK_A) * blockDim.x + t;  // float4 idx
        const size_t n4  = (size_t)N_NODES  * EMB / 4;
        const size_t au4 = (size_t)N_AUTHORS * EMB / 4;
        if (i >= n4) return;
        float4 v = (i < au4) ? ((const float4*)a)[i] : ((const float4*)p)[i - au4];
        ((float4*)ego_out)[i] = v;
        ushort4 b;
        b.x = f2bf(v.x); b.y = f2bf(v.y); b.z = f2bf(v.z); b.w = f2bf(v.w);
        ((ushort4*)x0)[i] = b;
    }
}

// ---------------- L1 scan over NSC entries (block totals -> btot) -----------
__global__ void lgcn_scan_l1(const unsigned* __restrict__ counts,
                             unsigned* __restrict__ scanned,
                             unsigned* __restrict__ btot) {
    __shared__ unsigned s[1024];
    int t = threadIdx.x;
    int i = blockIdx.x * 1024 + t;
    unsigned v = (i < NSC) ? counts[i] : 0u;
    s[t] = v;
    __syncthreads();
    for (int d = 1; d < 1024; d <<= 1) {
        unsigned u = (t >= d) ? s[t - d] : 0u;
        __syncthreads();
        s[t] += u;
        __syncthreads();
    }
    if (i < NSC) scanned[i] = s[t] - v;     // exclusive within block
    if (t == 1023) btot[blockIdx.x] = s[1023];
}

// in-block top-level prefix of btot (43 entries) -> LDS
__device__ __forceinline__ void btot_prefix(const unsigned* __restrict__ btot,
                                            unsigned* __restrict__ btex) {
    if (threadIdx.x == 0) {
        unsigned run = 0;
        for (int i = 0; i < NBS1; ++i) { btex[i] = run; run += btot[i]; }
    }
    __syncthreads();
}

// ---------------- A1: bin edges into EXCLUSIVE per-(block,bucket) runs ------
__global__ void lgcn_a1_bin(const int* __restrict__ rows,
                            const int* __restrict__ cols,
                            const float* __restrict__ vals,
                            const unsigned* __restrict__ scanned,
                            const unsigned* __restrict__ btot,
                            float2* __restrict__ stage) {
    __shared__ unsigned cur[K_B];
    __shared__ unsigned btex[NBS1];
    btot_prefix(btot, btex);
    int t = threadIdx.x;
    for (int i = t; i < K_B; i += blockDim.x) {
        unsigned idx = (unsigned)i * NBLK_A + blockIdx.x;
        cur[i] = scanned[idx] + btex[idx >> 10];
    }
    __syncthreads();
    int base = blockIdx.x * CHUNK;
    int end  = base + CHUNK; if (end > N_EDGES) end = N_EDGES;
    for (int e = base + t; e < end; e += blockDim.x) {
        int r = rows[e];
        unsigned pos = atomicAdd(&cur[r >> BSHIFT], 1u);
        unsigned packed = ((unsigned)(r & 1023) << 18) | (unsigned)cols[e];
        stage[pos] = make_float2(__uint_as_float(packed), vals[e]);
    }
}

// ---------------- B: per-bucket place; self-counts rows; emits row_start ----
__global__ void lgcn_place(const unsigned* __restrict__ scanned,
                           const unsigned* __restrict__ btot,
                           const float2* __restrict__ stage,
                           float2* __restrict__ se,
                           unsigned* __restrict__ row_start) {
    __shared__ unsigned cur[1 << BSHIFT];
    __shared__ unsigned tsum[256];
    __shared__ unsigned btex[NBS1];
    btot_prefix(btot, btex);
    int b  = blockIdx.x;
    int rb = b << BSHIFT;
    int nrows = N_NODES - rb; if (nrows > (1 << BSHIFT)) nrows = 1 << BSHIFT;
    int t = threadIdx.x;

    unsigned i0 = (unsigned)b * NBLK_A;
    unsigned base = scanned[i0] + btex[i0 >> 10];
    unsigned span1;
    if (b + 1 < K_B) {
        unsigned i1 = (unsigned)(b + 1) * NBLK_A;
        span1 = scanned[i1] + btex[i1 >> 10];
    } else span1 = N_EDGES;

    // pass 1: count this bucket's rows from the staged records (L2-hot span)
    for (int i = t; i < (1 << BSHIFT); i += 256) cur[i] = 0;
    __syncthreads();
    for (unsigned p = base + t; p < span1; p += 256)
        atomicAdd(&cur[__float_as_uint(stage[p].x) >> 18], 1u);
    __syncthreads();

    // block scan of the 1024 counts (4 per thread) -> cursors + row_start
    unsigned c[4], s = 0;
#pragma unroll
    for (int k = 0; k < 4; ++k) { c[k] = cur[t * 4 + k]; s += c[k]; }
    tsum[t] = s;
    __syncthreads();
    for (int d = 1; d < 256; d <<= 1) {
        unsigned u = (t >= d) ? tsum[t - d] : 0u;
        __syncthreads();
        tsum[t] += u;
        __syncthreads();
    }
    unsigned run = base + (tsum[t] - s);
    __syncthreads();            // everyone done reading cur before overwrite
#pragma unroll
    for (int k = 0; k < 4; ++k) {
        int i = t * 4 + k;
        cur[i] = run;
        if (i < nrows) row_start[rb + i] = run;
        run += c[k];
    }
    if (b == K_B - 1 && t == 0) row_start[N_NODES] = N_EDGES;
    __syncthreads();

    // pass 2: place into row-sorted se (writes land in ~65KB L2 window)
    for (unsigned p = base + t; p < span1; p += 256) {
        float2 v = stage[p];
        unsigned u = __float_as_uint(v.x);
        unsigned pos = atomicAdd(&cur[u >> 18], 1u);
        se[pos] = make_float2(__int_as_float((int)(u & 0x3FFFFu)), v.y);
    }
}

// ---------------- SpMM: one wave per 2 rows, 8-lane edge groups, v2f math ---
// MODE 0: gather bf16 (xb), write fp8 y.
// MODE 1: gather fp8 (x8), write fp8 y.
// MODE 2: gather fp8 y2 (x8), fused merge with bf16 ego + fp8 y1 + fp8 y2.
template <int MODE>
__global__ void lgcn_spmm(const unsigned* __restrict__ rs,
                          const float2* __restrict__ se,
                          const ushort* __restrict__ xb,
                          const unsigned char* __restrict__ x8,
                          unsigned char* __restrict__ y8,
                          const ushort* __restrict__ egob,
                          const unsigned char* __restrict__ y18,
                          float* __restrict__ out) {
    int w    = blockIdx.x * (blockDim.x >> 6) + (threadIdx.x >> 6);
    int lane = threadIdx.x & 63;
    int r0   = w << 1;
    if (r0 >= N_NODES) return;
    unsigned jA   = rs[r0];
    unsigned endA = rs[r0 + 1];
    unsigned jB   = endA;
    unsigned endB = rs[r0 + 2];
    const int g  = lane >> 3;
    const int d8 = (lane & 7) << 3;    // 8 bf16 elements or 8 fp8 bytes
    v2f A0 = {0.f, 0.f}, A1 = A0, A2 = A0, A3 = A0;
    v2f B0 = A0, B1 = A0, B2 = A0, B3 = A0;

#define BATCH8(JB, END, P0, P1, P2, P3)                                       \
    {                                                                         \
        unsigned idx = (JB) + g;                                              \
        float2 e;                                                             \
        if (idx < (END)) e = se[idx];                                         \
        else { e.x = __int_as_float(0); e.y = 0.f; }                          \
        v2f ey = mkv2(e.y, e.y);                                              \
        if constexpr (MODE == 0) {                                            \
            const uint4 xv = *(const uint4*)(xb + ((size_t)__float_as_int(e.x) << 6) + d8); \
            P0 += ey * bfv2(xv.x);                                            \
            P1 += ey * bfv2(xv.y);                                            \
            P2 += ey * bfv2(xv.z);                                            \
            P3 += ey * bfv2(xv.w);                                            \
        } else {                                                              \
            const uint2 xv = *(const uint2*)(x8 + ((size_t)__float_as_int(e.x) << 6) + d8); \
            P0 += ey * __builtin_amdgcn_cvt_pk_f32_fp8((int)xv.x, false);     \
            P1 += ey * __builtin_amdgcn_cvt_pk_f32_fp8((int)xv.x, true);      \
            P2 += ey * __builtin_amdgcn_cvt_pk_f32_fp8((int)xv.y, false);     \
            P3 += ey * __builtin_amdgcn_cvt_pk_f32_fp8((int)xv.y, true);      \
        }                                                                     \
    }

    // both rows' first batches: 16 independent gathers in flight
    BATCH8(jA, endA, A0, A1, A2, A3)
    BATCH8(jB, endB, B0, B1, B2, B3)
    jA += 8; jB += 8;
    while (jA < endA) { BATCH8(jA, endA, A0, A1, A2, A3) jA += 8; }
    while (jB < endB) { BATCH8(jB, endB, B0, B1, B2, B3) jB += 8; }
#undef BATCH8

    A0 = red_v2(A0); A1 = red_v2(A1); A2 = red_v2(A2); A3 = red_v2(A3);
    B0 = red_v2(B0); B1 = red_v2(B1); B2 = red_v2(B2); B3 = red_v2(B3);

    if (g == 0) {
#define EMIT(ROW, P0, P1, P2, P3)                                             \
    {                                                                         \
        size_t o = ((size_t)(ROW) << 6) + d8;                                 \
        if constexpr (MODE == 2) {                                            \
            uint4 ue = *(const uint4*)(egob + o);                             \
            uint2 u1 = *(const uint2*)(y18 + o);                              \
            uint2 u2 = *(const uint2*)(x8 + o);                               \
            v2f q = mkv2(0.25f, 0.25f);                                       \
            v2f r0 = (bfv2(ue.x) + __builtin_amdgcn_cvt_pk_f32_fp8((int)u1.x, false) \
                      + __builtin_amdgcn_cvt_pk_f32_fp8((int)u2.x, false) + P0) * q; \
            v2f r1 = (bfv2(ue.y) + __builtin_amdgcn_cvt_pk_f32_fp8((int)u1.x, true)  \
                      + __builtin_amdgcn_cvt_pk_f32_fp8((int)u2.x, true) + P1) * q; \
            v2f r2 = (bfv2(ue.z) + __builtin_amdgcn_cvt_pk_f32_fp8((int)u1.y, false) \
                      + __builtin_amdgcn_cvt_pk_f32_fp8((int)u2.y, false) + P2) * q; \
            v2f r3 = (bfv2(ue.w) + __builtin_amdgcn_cvt_pk_f32_fp8((int)u1.y, true)  \
                      + __builtin_amdgcn_cvt_pk_f32_fp8((int)u2.y, true) + P3) * q; \
            float4 lo, hi;                                                    \
            lo.x = r0.x; lo.y = r0.y; lo.z = r1.x; lo.w = r1.y;               \
            hi.x = r2.x; hi.y = r2.y; hi.z = r3.x; hi.w = r3.y;               \
            *(float4*)(out + o)     = lo;                                     \
            *(float4*)(out + o + 4) = hi;                                     \
        } else {                                                              \
            int w0 = __builtin_amdgcn_cvt_pk_fp8_f32(P0.x, P0.y, 0, false);   \
            w0     = __builtin_amdgcn_cvt_pk_fp8_f32(P1.x, P1.y, w0, true);   \
            int w1 = __builtin_amdgcn_cvt_pk_fp8_f32(P2.x, P2.y, 0, false);   \
            w1     = __builtin_amdgcn_cvt_pk_fp8_f32(P3.x, P3.y, w1, true);   \
            uint2 ov8; ov8.x = (unsigned)w0; ov8.y = (unsigned)w1;            \
            *(uint2*)(y8 + o) = ov8;                                          \
        }                                                                     \
    }
        EMIT(r0, A0, A1, A2, A3)
        EMIT(r0 + 1, B0, B1, B2, B3)
#undef EMIT
    }
}

extern "C" void kernel_launch(void* const* d_in, const int* in_sizes, int n_in,
                              void* d_out, int out_size, void* d_ws, size_t ws_size,
                              hipStream_t stream) {
    const float* author = (const float*)d_in[0];
    const float* paper  = (const float*)d_in[1];
    const int*   rows   = (const int*)d_in[2];
    const int*   cols   = (const int*)d_in[3];
    const float* vals   = (const float*)d_in[4];

    float* ego_out = (float*)d_out;                           // 150000*64 f32
    float* acc     = (float*)d_out + (size_t)N_NODES * EMB;   // author||paper f32

    // workspace layout (~50 MB)
    char* w = (char*)d_ws;
    float2*   se        = (float2*)w;   w += (size_t)N_EDGES * sizeof(float2);       // 9.6 MB
    float2*   stage     = (float2*)w;   w += (size_t)N_EDGES * sizeof(float2);       // 9.6 MB (dead after place -> y1_8)
    ushort*   xbE       = (ushort*)w;   w += (size_t)N_NODES * EMB * sizeof(ushort); // 19.2 MB (bf16 ego)
    unsigned char* y2_8 = (unsigned char*)w; w += (size_t)N_NODES * EMB;             // 9.6 MB (fp8 y2)
    unsigned* row_start = (unsigned*)w; w += (size_t)(N_NODES + 1) * 4;              // 0.6 MB
    unsigned* bcounts   = (unsigned*)w; w += (size_t)NSC * 4;                        // 172 KB
    unsigned* bscanned  = (unsigned*)w; w += (size_t)NSC * 4;                        // 172 KB
    unsigned* btot      = (unsigned*)w; w += 64 * 4;
    unsigned char* y1_8 = (unsigned char*)stage;   // alias: stage dead after place

    const int BLK = 256;
    const int g_vec  = (int)(((size_t)N_NODES * EMB / 4 + BLK - 1) / BLK);
    const int g_spmm = ((N_NODES / 2) + 3) / 4;       // 2 rows/wave, 4 waves/block

    // fused: bucket histogram + ego init
    lgcn_hist_init<<<NBLK_A + g_vec, BLK, 0, stream>>>(rows, bcounts,
                                                       author, paper, ego_out, xbE);

    // L1 scan (top-level prefix folded into consumers)
    lgcn_scan_l1<<<NBS1, 1024, 0, stream>>>(bcounts, bscanned, btot);

    // bin into exclusive staging runs, then place (also emits row_start)
    lgcn_a1_bin<<<NBLK_A, BLK, 0, stream>>>(rows, cols, vals, bscanned, btot, stage);
    lgcn_place<<<K_B, BLK, 0, stream>>>(bscanned, btot, stage, se, row_start);

    // L1: gather bf16 ego -> y1 fp8
    lgcn_spmm<0><<<g_spmm, BLK, 0, stream>>>(row_start, se, xbE, nullptr,
                                             y1_8, nullptr, nullptr, nullptr);
    // L2: gather fp8 y1 -> y2 fp8
    lgcn_spmm<1><<<g_spmm, BLK, 0, stream>>>(row_start, se, nullptr, y1_8,
                                             y2_8, nullptr, nullptr, nullptr);
    // L3: gather fp8 y2, fused merge -> out
    lgcn_spmm<2><<<g_spmm, BLK, 0, stream>>>(row_start, se, nullptr, y2_8,
                                             nullptr, xbE, y1_8, acc);
}